// Round 5
// baseline (1499.053 us; speedup 1.0000x reference)
//
#include <hip/hip_runtime.h>
#include <hip/hip_bf16.h>
#include <math.h>

constexpr int Bz = 1024;
constexpr int C0 = 271;   // input channels
constexpr int CP0 = 288;  // padded to 9*32
constexpr int Tt = 281;   // time
constexpr int TR = 292;   // padded rows per batch: row = t+1; rows 0,282..291 zero
constexpr int H1 = 128;
constexpr int H2 = 256;
constexpr int NCLS = 1854;
constexpr int ED = 16;
constexpr float BN_INV = 0.9999950000374996f;  // 1/sqrt(1+1e-5)

typedef __attribute__((ext_vector_type(8))) short s16x8;
typedef __attribute__((ext_vector_type(16))) float f32x16;

__device__ __forceinline__ float gelu_f(float v) {
    return 0.5f * v * (1.0f + erff(v * 0.7071067811865475f));
}
__device__ __forceinline__ float bf2f(short s) {
    return __builtin_bit_cast(float, ((unsigned int)(unsigned short)s) << 16);
}
__device__ __forceinline__ short f2bf(float f) {
    return __builtin_bit_cast(short, __float2bfloat16(f));
}

typedef unsigned int u32;
typedef const __attribute__((address_space(1))) u32 gu32;
typedef __attribute__((address_space(3))) u32 lu32;

__device__ __forceinline__ void gl16(const void* g, void* l) {
    __builtin_amdgcn_global_load_lds((gu32*)(uintptr_t)g, (lu32*)(uintptr_t)l, 16, 0, 0);
}
template<int N> __device__ __forceinline__ void waitv() {
    asm volatile("s_waitcnt vmcnt(%0)" :: "i"(N) : "memory");
}
__device__ __forceinline__ void hard_barrier() {
    __builtin_amdgcn_s_barrier();
    __builtin_amdgcn_sched_barrier(0);
}

// ---------------- prep kernels ----------------

__global__ void zrows_k(short* base, int C) {
    const int b = blockIdx.x;
    const int n = 11 * (C / 8);
    for (int i = threadIdx.x; i < n; i += 256) {
        int ri = i / (C / 8), c8 = i - ri * (C / 8);
        int row = (ri == 0) ? 0 : 281 + ri;   // 0, 282..291
        *(int4*)(base + ((size_t)b * TR + row) * C + c8 * 8) = make_int4(0, 0, 0, 0);
    }
}

__global__ void zerof_k(float* p, int n) {
    int i = blockIdx.x * 256 + threadIdx.x;
    if (i < n) p[i] = 0.f;
}

__global__ void softmax_rows_k(const float* __restrict__ a, float* __restrict__ o, int n) {
    __shared__ float red[256];
    const int row = blockIdx.x, tid = threadIdx.x;
    const float* r = a + (size_t)row * n;
    float m = -1e30f;
    for (int i = tid; i < n; i += 256) m = fmaxf(m, r[i]);
    red[tid] = m; __syncthreads();
    for (int s = 128; s > 0; s >>= 1) { if (tid < s) red[tid] = fmaxf(red[tid], red[tid + s]); __syncthreads(); }
    m = red[0]; __syncthreads();
    float acc = 0.f;
    for (int i = tid; i < n; i += 256) acc += expf(r[i] - m);
    red[tid] = acc; __syncthreads();
    for (int s = 128; s > 0; s >>= 1) { if (tid < s) red[tid] += red[tid + s]; __syncthreads(); }
    const float inv = 1.0f / red[0];
    for (int i = tid; i < n; i += 256) o[(size_t)row * n + i] = expf(r[i] - m) * inv;
}

// M[o][c] = sum_i sa_w[o][i] * attnS[i][c]
__global__ void gemm_M_k(const float* __restrict__ sa_w, const float* __restrict__ attnS,
                         float* __restrict__ M) {
    int idx = blockIdx.x * 256 + threadIdx.x;
    if (idx >= H1 * C0) return;
    int o = idx / C0, c = idx - o * C0;
    float s = 0.f;
    for (int i = 0; i < C0; ++i) s = fmaf(sa_w[(size_t)o * C0 + i], attnS[(size_t)i * C0 + c], s);
    M[idx] = s;
}

// fragment-order weights: chunk r=((cc*K+k)*OB32+ob), kk; lane holds o=ob*32+(l&31),
// c = cc*32 + kk*16 + (l>>5)*8 + j
__global__ void wfrag_k(const float* __restrict__ w, short* __restrict__ out,
                        int CIN, int O, int K, int NC) {
    int idx = blockIdx.x * 256 + threadIdx.x;
    int OB32 = O / 32;
    int total = NC * K * OB32 * 2 * 512;
    if (idx >= total) return;
    int j = idx & 7, lane = (idx >> 3) & 63, kk = (idx >> 9) & 1, r = idx >> 10;
    int ob = r % OB32, r2 = r / OB32;
    int k = r2 % K, cc = r2 / K;
    int o = ob * 32 + (lane & 31);
    int c = cc * 32 + kk * 16 + (lane >> 5) * 8 + j;
    float v = (c < CIN) ? w[((size_t)o * CIN + c) * K + k] : 0.f;
    out[idx] = f2bf(v);
}

// stage-A fused weights, fragment order, NC=10 (CIN padded 320): val = sum_h subj_w[s][o][h]*M[h][c]
__global__ void msubA_k(const float* __restrict__ subj_w, const float* __restrict__ M,
                        short* __restrict__ out) {
    int idx = blockIdx.x * 256 + threadIdx.x;
    const int per_s = 10 * 1 * 4 * 2 * 512;   // NC=10,K=1,OB32=4
    if (idx >= 4 * per_s) return;
    int s = idx / per_s, rem = idx % per_s;
    int j = rem & 7, lane = (rem >> 3) & 63, kk = (rem >> 9) & 1, r = rem >> 10;
    int ob = r % 4, cc = r / 4;               // K=1, cc 0..9
    int o = ob * 32 + (lane & 31);
    int c = cc * 32 + kk * 16 + (lane >> 5) * 8 + j;
    float a = 0.f;
    if (c < C0) {
        const float* wr = subj_w + ((size_t)s * 128 + o) * 128;
        for (int h = 0; h < 128; ++h) a = fmaf(wr[h], M[(size_t)h * C0 + c], a);
    }
    out[idx] = f2bf(a);
}

__global__ void biasS_k(const float* __restrict__ subj_w, const float* __restrict__ sa_b,
                        const float* __restrict__ subj_b, float* __restrict__ biasS) {
    int idx = blockIdx.x * 256 + threadIdx.x;
    if (idx >= 4 * H1) return;
    int s = idx >> 7, o = idx & 127;
    const float* wr = subj_w + ((size_t)s * H1 + o) * H1;
    float a = subj_b[idx];
    for (int h = 0; h < H1; ++h) a = fmaf(wr[h], sa_b[h], a);
    biasS[idx] = a;
}

// X [b][c][t] fp32 -> xT [b][row=t+1][288] bf16
__global__ void xpose_k(const float* __restrict__ X, short* __restrict__ xT) {
    __shared__ float tile[32][33];
    int b = blockIdx.z;
    int t0 = blockIdx.x * 32, c0 = blockIdx.y * 32;
    int tx = threadIdx.x, ty = threadIdx.y;
    #pragma unroll
    for (int i = 0; i < 4; ++i) {
        int c = c0 + ty + i * 8, t = t0 + tx;
        float v = 0.f;
        if (c < C0 && t < Tt) v = X[((size_t)b * C0 + c) * Tt + t];
        tile[ty + i * 8][tx] = v;
    }
    __syncthreads();
    #pragma unroll
    for (int i = 0; i < 4; ++i) {
        int t = t0 + ty + i * 8, c = c0 + tx;
        if (t < Tt) xT[((size_t)b * TR + t + 1) * CP0 + c] = f2bf(tile[tx][ty + i * 8]);
    }
}

// ---------------- pipelined conv kernel ----------------
// Block: NB batches x O_BLK outputs x 96 t. 4-wave blocks (2/SIMD, 256-reg budget).
// X window (104 rows) staged ONCE via global_load_lds (XOR unit swizzle u^(rl&7)).
// K-loop: ZERO barriers; A fragments straight from L2 (fully unrolled -> compiler
// pipelines loads deep in the big register budget); B via ds_read_b128 from LDS.
// POOL variant fuses the global average pool (no output write).

template<int K, int NCC, int O_BLK, int NB, bool GELU, bool HASRES, bool POOL>
__global__ __launch_bounds__(NB * (O_BLK / 64) * 64, 2)
void convPL(const short* __restrict__ xin, int XC,
            const short* __restrict__ wfragp,
            const float* __restrict__ bias,
            const float* __restrict__ gamma, const float* __restrict__ beta,
            const short* __restrict__ res, short* __restrict__ outp,
            float* __restrict__ pooled,
            const int* __restrict__ sidx, int wsub, int bsub)
{
    constexpr int OW   = O_BLK / 64;
    constexpr int NW   = NB * OW;
    constexpr int NT   = NW * 64;
    constexpr int OB32 = O_BLK / 32;
    constexpr int ROWB = NCC * 64;           // bytes per staged row
    constexpr int CH   = 104 * ROWB / 1024;  // 1KB chunks per batch slab
    constexpr int OUTB = 96 * O_BLK * 2;
    constexpr int SLAB = CH * 1024;
    constexpr int REG  = SLAB > OUTB ? SLAB : OUTB;
    constexpr int O2   = O_BLK * 2;

    __shared__ __align__(16) char smem[NB * REG];

    const int t0   = blockIdx.x * 96;
    const int b0   = blockIdx.y * NB;
    const int tid  = threadIdx.x;
    const int lane = tid & 63, wv = tid >> 6;
    const int l31  = lane & 31, hi = lane >> 5;
    const int bq   = wv / OW;
    const int wvo  = wv % OW;

    int subj = sidx ? sidx[b0] : 0;
    const short* wb = wfragp + (size_t)subj * wsub;
    const float* bb = bias + (size_t)subj * bsub;

    // ---- stage X window rows [t0-1 .. t0+102] (buffer rows t0 .. t0+103, clamped) ----
    for (int i = wv; i < NB * CH; i += NW) {
        int bql = i / CH, ic = i - bql * CH;
        int pos = ic * 1024 + lane * 16;
        int rl  = pos / ROWB;
        int u   = (pos - rl * ROWB) >> 4;
        int usrc = u ^ (rl & 7);
        int br  = t0 + rl;
        if (br > 291) br = 291;
        gl16(xin + ((size_t)(b0 + bql) * TR + br) * XC + usrc * 8,
             smem + bql * REG + ic * 1024);
    }
    waitv<0>();
    hard_barrier();

    f32x16 acc[2][3];
    #pragma unroll
    for (int i = 0; i < 2; ++i)
        #pragma unroll
        for (int j = 0; j < 3; ++j)
            #pragma unroll
            for (int e = 0; e < 16; ++e) acc[i][j][e] = 0.f;

    const char* Xb = smem + bq * REG;

    // ---- barrier-free K-loop, fully unrolled ----
    #pragma unroll
    for (int cc = 0; cc < NCC; ++cc) {
        #pragma unroll
        for (int k = 0; k < K; ++k) {
            #pragma unroll
            for (int kk = 0; kk < 2; ++kk) {
                const short* ap = wb + ((size_t)((((cc * K + k) * OB32 + wvo * 2) * 2) + kk)) * 512;
                s16x8 a0 = *(const s16x8*)(ap + lane * 8);
                s16x8 a1 = *(const s16x8*)(ap + 1024 + lane * 8);
                __builtin_amdgcn_s_setprio(1);
                #pragma unroll
                for (int ts = 0; ts < 3; ++ts) {
                    int rl = ts * 32 + l31 + k;
                    s16x8 bv = *(const s16x8*)(Xb + rl * ROWB +
                                (((cc * 4 + kk * 2 + hi) ^ (rl & 7)) << 4));
                    acc[0][ts] = __builtin_amdgcn_mfma_f32_32x32x16_bf16(a0, bv, acc[0][ts], 0, 0, 0);
                    acc[1][ts] = __builtin_amdgcn_mfma_f32_32x32x16_bf16(a1, bv, acc[1][ts], 0, 0, 0);
                }
                __builtin_amdgcn_s_setprio(0);
            }
        }
    }

    const int b = b0 + bq;

    if constexpr (POOL) {
        // fused global-average-pool epilogue: bias/bn (+res) + gelu, reduce over t, atomic add
        float ps[2][16];
        #pragma unroll
        for (int os = 0; os < 2; ++os)
            #pragma unroll
            for (int rg = 0; rg < 16; ++rg) ps[os][rg] = 0.f;
        #pragma unroll
        for (int os = 0; os < 2; ++os) {
            #pragma unroll
            for (int rg = 0; rg < 16; ++rg) {
                const int oc = wvo * 64 + os * 32 + (rg & 3) + 8 * (rg >> 2) + 4 * hi;
                const float bv = bb[oc];
                const float g0 = gamma ? gamma[oc] * BN_INV : 1.f;
                const float e0 = beta ? beta[oc] : 0.f;
                #pragma unroll
                for (int ts = 0; ts < 3; ++ts) {
                    int t = t0 + ts * 32 + l31;
                    float v = (acc[os][ts][rg] + bv) * g0 + e0;
                    if (HASRES) v += bf2f(res[((size_t)b * TR + t + 1) * O_BLK + oc]);
                    if (GELU) v = gelu_f(v);
                    if (t < Tt) ps[os][rg] += v;
                }
            }
        }
        #pragma unroll
        for (int os = 0; os < 2; ++os) {
            #pragma unroll
            for (int rg = 0; rg < 16; ++rg) {
                float s = ps[os][rg];
                s += __shfl_xor(s, 1);
                s += __shfl_xor(s, 2);
                s += __shfl_xor(s, 4);
                s += __shfl_xor(s, 8);
                s += __shfl_xor(s, 16);
                if (l31 == 0) {
                    const int oc = wvo * 64 + os * 32 + (rg & 3) + 8 * (rg >> 2) + 4 * hi;
                    atomicAdd(pooled + (size_t)b * H2 + oc, s * (1.0f / 281.0f));
                }
            }
        }
        return;
    }

    // ---- epilogue: bias+bn to bf16 via swizzled LDS, coalesced store (+res,+gelu) ----
    __syncthreads();
    #pragma unroll
    for (int os = 0; os < 2; ++os) {
        #pragma unroll
        for (int rq = 0; rq < 4; ++rq) {
            #pragma unroll
            for (int rp = 0; rp < 2; ++rp) {
                const int oc = wvo * 64 + os * 32 + 8 * rq + rp * 2 + 4 * hi;
                const float bv0 = bb[oc], bv1 = bb[oc + 1];
                const float g0 = gamma ? gamma[oc] * BN_INV : 1.f;
                const float g1 = gamma ? gamma[oc + 1] * BN_INV : 1.f;
                const float e0 = beta ? beta[oc] : 0.f;
                const float e1 = beta ? beta[oc + 1] : 0.f;
                const int r0 = rq * 4 + rp * 2;
                #pragma unroll
                for (int ts = 0; ts < 3; ++ts) {
                    float v0 = (acc[os][ts][r0] + bv0) * g0 + e0;
                    float v1 = (acc[os][ts][r0 + 1] + bv1) * g1 + e1;
                    int tl = ts * 32 + l31;
                    int byte = (bq * 96 + tl) * O2 + ((oc * 2) ^ ((tl & 15) << 4));
                    __hip_bfloat162 pk;
                    pk.x = __float2bfloat16(v0);
                    pk.y = __float2bfloat16(v1);
                    *(__hip_bfloat162*)(smem + byte) = pk;
                }
            }
        }
    }
    __syncthreads();
    constexpr int RCH = O_BLK / 8;
    for (int qq = tid; qq < NB * 96 * RCH; qq += NT) {
        int bql = qq / (96 * RCH), rem = qq - bql * (96 * RCH);
        int r = rem / RCH, cp = rem - r * RCH;
        int t = t0 + r;
        if (t >= Tt) continue;
        s16x8 hv = *(const s16x8*)(smem + (bql * 96 + r) * O2 + ((cp * 16) ^ ((r & 15) << 4)));
        size_t orow = ((size_t)(b0 + bql) * TR + t + 1) * O_BLK + cp * 8;
        s16x8 rv;
        if (HASRES) rv = *(const s16x8*)(res + orow);
        s16x8 ov;
        #pragma unroll
        for (int j = 0; j < 8; ++j) {
            float v = bf2f(hv[j]);
            if (HASRES) v += bf2f(rv[j]);
            if (GELU) v = gelu_f(v);
            ov[j] = f2bf(v);
        }
        *(s16x8*)(outp + orow) = ov;
    }
}

// ---------------- head kernels ----------------

__global__ void head1_k(const float* __restrict__ pooled, const float* __restrict__ emb,
                        const int* __restrict__ sidx, const float* __restrict__ w1,
                        const float* __restrict__ b1, float* __restrict__ hout) {
    int idx = blockIdx.x * 256 + threadIdx.x;
    if (idx >= Bz * H1) return;
    int b = idx >> 7, j = idx & 127;
    const float* wr = w1 + (size_t)j * (H2 + ED);
    const float* pr = pooled + (size_t)b * H2;
    float a = b1[j];
    for (int i = 0; i < H2; ++i) a = fmaf(pr[i], wr[i], a);
    const float* er = emb + (size_t)sidx[b] * ED;
    #pragma unroll
    for (int e = 0; e < ED; ++e) a = fmaf(er[e], wr[H2 + e], a);
    hout[idx] = fmaxf(a, 0.f);
}

__global__ __launch_bounds__(256)
void head2_k(const float* __restrict__ h, const float* __restrict__ w2,
             const float* __restrict__ b2, float* __restrict__ out) {
    const int n0 = blockIdx.x * 64;
    const int b0 = blockIdx.y * 16;
    __shared__ float hs[16][128];
    __shared__ float w2s[64][129];
    const int tid = threadIdx.x;
    for (int idx = tid; idx < 16 * 128; idx += 256) {
        int bl = idx >> 7, j = idx & 127;
        hs[bl][j] = h[(size_t)(b0 + bl) * H1 + j];
    }
    for (int idx = tid; idx < 64 * 128; idx += 256) {
        int nl = idx >> 7, j = idx & 127;
        int n = n0 + nl;
        w2s[nl][j] = (n < NCLS) ? w2[(size_t)n * H1 + j] : 0.f;
    }
    __syncthreads();
    const int nl = tid & 63, bg = tid >> 6;
    float acc[4] = {0.f, 0.f, 0.f, 0.f};
    for (int j = 0; j < 128; ++j) {
        const float wv = w2s[nl][j];
        #pragma unroll
        for (int bb = 0; bb < 4; ++bb) acc[bb] = fmaf(wv, hs[bg * 4 + bb][j], acc[bb]);
    }
    const int n = n0 + nl;
    if (n < NCLS) {
        const float bv = b2[n];
        #pragma unroll
        for (int bb = 0; bb < 4; ++bb)
            out[(size_t)(b0 + bg * 4 + bb) * NCLS + n] = acc[bb] + bv;
    }
}

// ---------------- host launch ----------------

extern "C" void kernel_launch(void* const* d_in, const int* in_sizes, int n_in,
                              void* d_out, int out_size, void* d_ws, size_t ws_size,
                              hipStream_t stream) {
    const float* X      = (const float*)d_in[0];
    const int*   sidx   = (const int*)  d_in[1];
    const float* attn   = (const float*)d_in[2];
    const float* sa_w   = (const float*)d_in[3];
    const float* sa_b   = (const float*)d_in[4];
    const float* subj_w = (const float*)d_in[5];
    const float* subj_b = (const float*)d_in[6];
    const float* b1c1w = (const float*)d_in[7];  const float* b1c1b = (const float*)d_in[8];
    const float* b1c2w = (const float*)d_in[9];  const float* b1c2b = (const float*)d_in[10];
    const float* b1g1  = (const float*)d_in[11]; const float* b1be1 = (const float*)d_in[12];
    const float* b1g2  = (const float*)d_in[13]; const float* b1be2 = (const float*)d_in[14];
    const float* b2c1w = (const float*)d_in[15]; const float* b2c1b = (const float*)d_in[16];
    const float* b2c2w = (const float*)d_in[17]; const float* b2c2b = (const float*)d_in[18];
    const float* b2g1  = (const float*)d_in[19]; const float* b2be1 = (const float*)d_in[20];
    const float* b2g2  = (const float*)d_in[21]; const float* b2be2 = (const float*)d_in[22];
    const float* b2skw = (const float*)d_in[23]; const float* b2skb = (const float*)d_in[24];
    const float* b3c1w = (const float*)d_in[25]; const float* b3c1b = (const float*)d_in[26];
    const float* b3c2w = (const float*)d_in[27]; const float* b3c2b = (const float*)d_in[28];
    const float* b3g1  = (const float*)d_in[29]; const float* b3be1 = (const float*)d_in[30];
    const float* b3g2  = (const float*)d_in[31]; const float* b3be2 = (const float*)d_in[32];
    const float* emb   = (const float*)d_in[33];
    const float* hw1   = (const float*)d_in[34]; const float* hb1 = (const float*)d_in[35];
    const float* hw2   = (const float*)d_in[36]; const float* hb2 = (const float*)d_in[37];
    float* out = (float*)d_out;
    (void)in_sizes; (void)n_in; (void)out_size; (void)ws_size;

    char* wsp = (char*)d_ws;
    size_t off = 0;
    auto allocF = [&](size_t n) {
        float* p = (float*)(wsp + off);
        off += ((n * sizeof(float)) + 255) & ~(size_t)255;
        return p;
    };
    auto allocS = [&](size_t n) {
        short* p = (short*)(wsp + off);
        off += ((n * sizeof(short)) + 255) & ~(size_t)255;
        return p;
    };
    float* attnS   = allocF((size_t)C0 * C0);
    float* Mmat    = allocF((size_t)H1 * C0);
    float* biasS   = allocF((size_t)4 * H1);
    float* pooled  = allocF((size_t)Bz * H2);
    float* hbuf    = allocF((size_t)Bz * H1);
    short* wStageA = allocS((size_t)4 * 10 * 4 * 2 * 512);    // per-subj 40960 (NC=10)
    short* wp_b1c1 = allocS((size_t)4 * 3 * 4 * 2 * 512);
    short* wp_b1c2 = allocS((size_t)4 * 3 * 4 * 2 * 512);
    short* wp_skip = allocS((size_t)4 * 1 * 8 * 2 * 512);
    short* wp_b2c1 = allocS((size_t)4 * 3 * 8 * 2 * 512);
    short* wp_b2c2 = allocS((size_t)8 * 3 * 8 * 2 * 512);
    short* wp_b3c1 = allocS((size_t)8 * 3 * 8 * 2 * 512);
    short* wp_b3c2 = allocS((size_t)8 * 3 * 8 * 2 * 512);
    short* xT   = allocS((size_t)Bz * TR * CP0 + 64);   // +64 pad: stageA over-read guard
    short* bufP = allocS((size_t)Bz * TR * H1);
    short* bufQ = allocS((size_t)Bz * TR * H1);
    short* bufR = allocS((size_t)Bz * TR * H2);
    short* bufS = allocS((size_t)Bz * TR * H2);

    // ---- zero margin rows + pooled ----
    zrows_k<<<Bz, 256, 0, stream>>>(xT, CP0);
    zrows_k<<<Bz, 256, 0, stream>>>(bufP, H1);
    zrows_k<<<Bz, 256, 0, stream>>>(bufQ, H1);
    zrows_k<<<Bz, 256, 0, stream>>>(bufR, H2);
    zrows_k<<<Bz, 256, 0, stream>>>(bufS, H2);
    zerof_k<<<(Bz * H2 + 255) / 256, 256, 0, stream>>>(pooled, Bz * H2);

    // ---- prep ----
    softmax_rows_k<<<C0, 256, 0, stream>>>(attn, attnS, C0);
    gemm_M_k<<<(H1 * C0 + 255) / 256, 256, 0, stream>>>(sa_w, attnS, Mmat);
    msubA_k<<<(4 * 40960 + 255) / 256, 256, 0, stream>>>(subj_w, Mmat, wStageA);
    biasS_k<<<2, 256, 0, stream>>>(subj_w, sa_b, subj_b, biasS);
    wfrag_k<<<(4*3*4*2*512 + 255) / 256, 256, 0, stream>>>(b1c1w, wp_b1c1, 128, 128, 3, 4);
    wfrag_k<<<(4*3*4*2*512 + 255) / 256, 256, 0, stream>>>(b1c2w, wp_b1c2, 128, 128, 3, 4);
    wfrag_k<<<(4*1*8*2*512 + 255) / 256, 256, 0, stream>>>(b2skw, wp_skip, 128, 256, 1, 4);
    wfrag_k<<<(4*3*8*2*512 + 255) / 256, 256, 0, stream>>>(b2c1w, wp_b2c1, 128, 256, 3, 4);
    wfrag_k<<<(8*3*8*2*512 + 255) / 256, 256, 0, stream>>>(b2c2w, wp_b2c2, 256, 256, 3, 8);
    wfrag_k<<<(8*3*8*2*512 + 255) / 256, 256, 0, stream>>>(b3c1w, wp_b3c1, 256, 256, 3, 8);
    wfrag_k<<<(8*3*8*2*512 + 255) / 256, 256, 0, stream>>>(b3c2w, wp_b3c2, 256, 256, 3, 8);
    xpose_k<<<dim3(9, 9, Bz), dim3(32, 8), 0, stream>>>(X, xT);

    // ---- conv stack (pipelined 4-wave kernels, 96-t blocks) ----
    // stageA: xT(288ch, NCC=10 padded) -> P(128), per-subject weights
    convPL<1, 10, 128, 1, false, false, false><<<dim3(3, Bz), 128, 0, stream>>>(
        xT, CP0, wStageA, biasS, nullptr, nullptr, nullptr, bufP, nullptr, sidx, 40960, 128);
    // block1: P -> Q (gelu+bn); Q (+res P) -> P in-place
    convPL<3, 4, 128, 2, true, false, false><<<dim3(3, Bz / 2), 256, 0, stream>>>(
        bufP, H1, wp_b1c1, b1c1b, b1g1, b1be1, nullptr, bufQ, nullptr, nullptr, 0, 0);
    convPL<3, 4, 128, 2, true, true, false><<<dim3(3, Bz / 2), 256, 0, stream>>>(
        bufQ, H1, wp_b1c2, b1c2b, b1g2, b1be2, bufP, bufP, nullptr, nullptr, 0, 0);
    // block2: skip P->S; c1 P->R; c2 R(+res S)->S in-place
    convPL<1, 4, 256, 1, false, false, false><<<dim3(3, Bz), 256, 0, stream>>>(
        bufP, H1, wp_skip, b2skb, nullptr, nullptr, nullptr, bufS, nullptr, nullptr, 0, 0);
    convPL<3, 4, 256, 1, true, false, false><<<dim3(3, Bz), 256, 0, stream>>>(
        bufP, H1, wp_b2c1, b2c1b, b2g1, b2be1, nullptr, bufR, nullptr, nullptr, 0, 0);
    convPL<3, 8, 256, 1, true, true, false><<<dim3(3, Bz), 256, 0, stream>>>(
        bufR, H2, wp_b2c2, b2c2b, b2g2, b2be2, bufS, bufS, nullptr, nullptr, 0, 0);
    // block3: c1 S->R; c2 R(+res S) -> fused avg-pool (no activation write)
    convPL<3, 8, 256, 1, true, false, false><<<dim3(3, Bz), 256, 0, stream>>>(
        bufS, H2, wp_b3c1, b3c1b, b3g1, b3be1, nullptr, bufR, nullptr, nullptr, 0, 0);
    convPL<3, 8, 256, 1, true, true, true><<<dim3(3, Bz), 256, 0, stream>>>(
        bufR, H2, wp_b3c2, b3c2b, b3g2, b3be2, bufS, nullptr, pooled, nullptr, 0, 0);

    // ---- head ----
    head1_k<<<(Bz * H1 + 255) / 256, 256, 0, stream>>>(pooled, emb, sidx, hw1, hb1, hbuf);
    head2_k<<<dim3((NCLS + 63) / 64, Bz / 16), 256, 0, stream>>>(hbuf, hw2, hb2, out);
}

// Round 6
// 1367.267 us; speedup vs baseline: 1.0964x; 1.0964x over previous
//
#include <hip/hip_runtime.h>
#include <hip/hip_bf16.h>
#include <math.h>

constexpr int Bz = 1024;
constexpr int C0 = 271;   // input channels
constexpr int CP0 = 288;  // padded to 9*32
constexpr int Tt = 281;   // time
constexpr int TR = 292;   // padded rows per batch: row = t+1; rows 0,282..291 zero
constexpr int H1 = 128;
constexpr int H2 = 256;
constexpr int NCLS = 1854;
constexpr int ED = 16;
constexpr float BN_INV = 0.9999950000374996f;  // 1/sqrt(1+1e-5)

typedef __attribute__((ext_vector_type(8))) short s16x8;
typedef __attribute__((ext_vector_type(16))) float f32x16;

__device__ __forceinline__ float gelu_f(float v) {
    return 0.5f * v * (1.0f + erff(v * 0.7071067811865475f));
}
__device__ __forceinline__ float bf2f(short s) {
    return __builtin_bit_cast(float, ((unsigned int)(unsigned short)s) << 16);
}
__device__ __forceinline__ short f2bf(float f) {
    return __builtin_bit_cast(short, __float2bfloat16(f));
}

typedef unsigned int u32;
typedef const __attribute__((address_space(1))) u32 gu32;
typedef __attribute__((address_space(3))) u32 lu32;

__device__ __forceinline__ void gl16(const void* g, void* l) {
    __builtin_amdgcn_global_load_lds((gu32*)(uintptr_t)g, (lu32*)(uintptr_t)l, 16, 0, 0);
}
template<int N> __device__ __forceinline__ void waitv() {
    asm volatile("s_waitcnt vmcnt(%0)" :: "i"(N) : "memory");
}
__device__ __forceinline__ void hard_barrier() {
    __builtin_amdgcn_sched_barrier(0);
    __builtin_amdgcn_s_barrier();
    __builtin_amdgcn_sched_barrier(0);
}

// ---------------- prep kernels ----------------

__global__ void zrows_k(short* base, int C) {
    const int b = blockIdx.x;
    const int n = 11 * (C / 8);
    for (int i = threadIdx.x; i < n; i += 256) {
        int ri = i / (C / 8), c8 = i - ri * (C / 8);
        int row = (ri == 0) ? 0 : 281 + ri;   // 0, 282..291
        *(int4*)(base + ((size_t)b * TR + row) * C + c8 * 8) = make_int4(0, 0, 0, 0);
    }
}

__global__ void softmax_rows_k(const float* __restrict__ a, float* __restrict__ o, int n) {
    __shared__ float red[256];
    const int row = blockIdx.x, tid = threadIdx.x;
    const float* r = a + (size_t)row * n;
    float m = -1e30f;
    for (int i = tid; i < n; i += 256) m = fmaxf(m, r[i]);
    red[tid] = m; __syncthreads();
    for (int s = 128; s > 0; s >>= 1) { if (tid < s) red[tid] = fmaxf(red[tid], red[tid + s]); __syncthreads(); }
    m = red[0]; __syncthreads();
    float acc = 0.f;
    for (int i = tid; i < n; i += 256) acc += expf(r[i] - m);
    red[tid] = acc; __syncthreads();
    for (int s = 128; s > 0; s >>= 1) { if (tid < s) red[tid] += red[tid + s]; __syncthreads(); }
    const float inv = 1.0f / red[0];
    for (int i = tid; i < n; i += 256) o[(size_t)row * n + i] = expf(r[i] - m) * inv;
}

// M[o][c] = sum_i sa_w[o][i] * attnS[i][c]
__global__ void gemm_M_k(const float* __restrict__ sa_w, const float* __restrict__ attnS,
                         float* __restrict__ M) {
    int idx = blockIdx.x * 256 + threadIdx.x;
    if (idx >= H1 * C0) return;
    int o = idx / C0, c = idx - o * C0;
    float s = 0.f;
    for (int i = 0; i < C0; ++i) s = fmaf(sa_w[(size_t)o * C0 + i], attnS[(size_t)i * C0 + c], s);
    M[idx] = s;
}

// fragment-order weights: chunk r=((cc*K+k)*OB32+ob), kk; lane holds o=ob*32+(l&31),
// c = cc*32 + kk*16 + (l>>5)*8 + j
__global__ void wfrag_k(const float* __restrict__ w, short* __restrict__ out,
                        int CIN, int O, int K, int NC) {
    int idx = blockIdx.x * 256 + threadIdx.x;
    int OB32 = O / 32;
    int total = NC * K * OB32 * 2 * 512;
    if (idx >= total) return;
    int j = idx & 7, lane = (idx >> 3) & 63, kk = (idx >> 9) & 1, r = idx >> 10;
    int ob = r % OB32, r2 = r / OB32;
    int k = r2 % K, cc = r2 / K;
    int o = ob * 32 + (lane & 31);
    int c = cc * 32 + kk * 16 + (lane >> 5) * 8 + j;
    float v = (c < CIN) ? w[((size_t)o * CIN + c) * K + k] : 0.f;
    out[idx] = f2bf(v);
}

// stage-A fused weights in fragment order, per subject: val = sum_h subj_w[s][o][h] * M[h][c]
__global__ void msubA_k(const float* __restrict__ subj_w, const float* __restrict__ M,
                        short* __restrict__ out) {
    int idx = blockIdx.x * 256 + threadIdx.x;
    const int per_s = 9 * 1 * 4 * 2 * 512;   // NC=9,K=1,OB32=4
    if (idx >= 4 * per_s) return;
    int s = idx / per_s, rem = idx % per_s;
    int j = rem & 7, lane = (rem >> 3) & 63, kk = (rem >> 9) & 1, r = rem >> 10;
    int ob = r % 4, cc = r / 4;               // K=1
    int o = ob * 32 + (lane & 31);
    int c = cc * 32 + kk * 16 + (lane >> 5) * 8 + j;
    float a = 0.f;
    if (c < C0) {
        const float* wr = subj_w + ((size_t)s * 128 + o) * 128;
        for (int h = 0; h < 128; ++h) a = fmaf(wr[h], M[(size_t)h * C0 + c], a);
    }
    out[idx] = f2bf(a);
}

__global__ void biasS_k(const float* __restrict__ subj_w, const float* __restrict__ sa_b,
                        const float* __restrict__ subj_b, float* __restrict__ biasS) {
    int idx = blockIdx.x * 256 + threadIdx.x;
    if (idx >= 4 * H1) return;
    int s = idx >> 7, o = idx & 127;
    const float* wr = subj_w + ((size_t)s * H1 + o) * H1;
    float a = subj_b[idx];
    for (int h = 0; h < H1; ++h) a = fmaf(wr[h], sa_b[h], a);
    biasS[idx] = a;
}

// X [b][c][t] fp32 -> xT [b][row=t+1][288] bf16
__global__ void xpose_k(const float* __restrict__ X, short* __restrict__ xT) {
    __shared__ float tile[32][33];
    int b = blockIdx.z;
    int t0 = blockIdx.x * 32, c0 = blockIdx.y * 32;
    int tx = threadIdx.x, ty = threadIdx.y;
    #pragma unroll
    for (int i = 0; i < 4; ++i) {
        int c = c0 + ty + i * 8, t = t0 + tx;
        float v = 0.f;
        if (c < C0 && t < Tt) v = X[((size_t)b * C0 + c) * Tt + t];
        tile[ty + i * 8][tx] = v;
    }
    __syncthreads();
    #pragma unroll
    for (int i = 0; i < 4; ++i) {
        int t = t0 + ty + i * 8, c = c0 + tx;
        if (t < Tt) xT[((size_t)b * TR + t + 1) * CP0 + c] = f2bf(tile[tx][ty + i * 8]);
    }
}

// ---------------- phased conv kernel: full-X-in-LDS, fine MFMA phases ----------------
// Per block: NB batches x O_BLK x full T, 12 (or 6) waves. X staged once via
// global_load_lds (XOR unit swizzle). Then (cc,k) phases: {prefetch next A-frags
// from L2 into ping-pong regs; 6 ds_read B->regs; barrier; setprio(1); 12 MFMA;
// setprio(0); barrier}. Barriers enforce role rotation (anti-convoy, T3/T5).

template<int NCCp, int ROWUp, int NW, int NCH>
__device__ __forceinline__ void conv_stage(
    const short* slabg, int XC, int cubase, char* lds, int wv, int lane)
{
    constexpr int ROWB = ROWUp * 16;
    for (int i = wv; i < NCH; i += NW) {
        int pos = i * 1024 + lane * 16;
        int rl = pos / ROWB;
        int up = (pos - rl * ROWB) >> 4;
        if (rl > 291) rl = 291;
        int ul = up ^ (rl & 7);
        int srcu = (ul < NCCp * 4) ? ul : 0;
        gl16(slabg + (size_t)rl * XC + (cubase + srcu) * 8, lds + i * 1024);
    }
}

template<int K, int CCB, int NPH, int ROWU, int OB32>
__device__ __forceinline__ void conv_phases(
    f32x16 (&acc)[2][3], const short* __restrict__ wb, const char* Xb,
    int tg, int lane, int l31, int hi, int wvo)
{
    constexpr int ROWB = ROWU * 16;
    constexpr int ROFF = 1 - (K - 1) / 2;
    s16x8 ab[2][4];
    // prologue: load A for phase 0
    #pragma unroll
    for (int i = 0; i < 4; ++i) {
        int ci = ((CCB * K + 0) * OB32 + wvo * 2 + (i >> 1)) * 2 + (i & 1);
        ab[0][i] = *(const s16x8*)(wb + (size_t)ci * 512 + lane * 8);
    }
    #pragma unroll
    for (int p = 0; p < NPH; ++p) {
        const int k  = p % K;
        const int cl = p / K;             // local cc (X slab units)
        // prefetch next phase's A fragments
        if (p + 1 < NPH) {
            const int cn = CCB + (p + 1) / K, kn = (p + 1) % K;
            #pragma unroll
            for (int i = 0; i < 4; ++i) {
                int ci = ((cn * K + kn) * OB32 + wvo * 2 + (i >> 1)) * 2 + (i & 1);
                ab[(p + 1) & 1][i] = *(const s16x8*)(wb + (size_t)ci * 512 + lane * 8);
            }
        }
        // B fragments from LDS
        s16x8 bf[2][3];
        #pragma unroll
        for (int kk = 0; kk < 2; ++kk)
            #pragma unroll
            for (int ts = 0; ts < 3; ++ts) {
                int rl = tg + ts * 32 + l31 + k + ROFF;
                bf[kk][ts] = *(const s16x8*)(Xb + (size_t)rl * ROWB +
                               (((cl * 4 + kk * 2 + hi) ^ (rl & 7)) << 4));
            }
        hard_barrier();
        __builtin_amdgcn_s_setprio(1);
        #pragma unroll
        for (int ts = 0; ts < 3; ++ts)
            #pragma unroll
            for (int kk = 0; kk < 2; ++kk) {
                acc[0][ts] = __builtin_amdgcn_mfma_f32_32x32x16_bf16(ab[p & 1][kk],     bf[kk][ts], acc[0][ts], 0, 0, 0);
                acc[1][ts] = __builtin_amdgcn_mfma_f32_32x32x16_bf16(ab[p & 1][2 + kk], bf[kk][ts], acc[1][ts], 0, 0, 0);
            }
        __builtin_amdgcn_s_setprio(0);
        hard_barrier();
    }
}

template<int K, int NCC_A, int ROWU_A, int NCC_B, int ROWU_B,
         int O_BLK, int NOW, int NB, bool GELU, bool HASRES, bool POOL>
__global__ __launch_bounds__(NOW * NB * 192)
void convPH(const short* __restrict__ xin, int XC,
            const short* __restrict__ wfrag,
            const float* __restrict__ bias,
            const float* __restrict__ gamma, const float* __restrict__ beta,
            const short* __restrict__ res, short* __restrict__ outp,
            float* __restrict__ pooled,
            const int* __restrict__ sidx, int wsub, int bsub)
{
    constexpr int NW    = NOW * NB * 3;
    constexpr int NT    = NW * 64;
    constexpr int OB32  = O_BLK / 32;
    constexpr int SLABB = ((292 * ROWU_A * 16) + 1023) & ~1023;
    constexpr int NCH_A = SLABB / 1024;
    constexpr int NCH_B = (292 * ROWU_B * 16 + 1023) / 1024;
    constexpr int O2    = O_BLK * 2;

    __shared__ __align__(16) char smem[NB * SLABB];

    const int b0   = blockIdx.x * NB;
    const int tid  = threadIdx.x;
    const int lane = tid & 63, wv = tid >> 6;
    const int l31  = lane & 31, hi = lane >> 5;
    const int bqw  = wv / (NOW * 3);
    const int w2   = wv % (NOW * 3);
    const int wvt  = w2 / NOW;          // t-group 0..2
    const int wvo  = w2 % NOW;          // o-group
    const int tg   = wvt * 96;

    int subj = sidx ? sidx[b0] : 0;
    const short* wb = wfrag + (size_t)subj * wsub;
    const float* bb = bias + (size_t)subj * bsub;

    f32x16 acc[2][3];
    #pragma unroll
    for (int i = 0; i < 2; ++i)
        #pragma unroll
        for (int j = 0; j < 3; ++j)
            #pragma unroll
            for (int e = 0; e < 16; ++e) acc[i][j][e] = 0.f;

    // ---- stage mega-phase A ----
    #pragma unroll
    for (int b = 0; b < NB; ++b)
        conv_stage<NCC_A, ROWU_A, NW, NCH_A>(
            xin + (size_t)(b0 + b) * TR * XC, XC, 0, smem + b * SLABB, wv, lane);
    waitv<0>();
    hard_barrier();

    const char* Xb = smem + bqw * SLABB;
    conv_phases<K, 0, NCC_A * K, ROWU_A, OB32>(acc, wb, Xb, tg, lane, l31, hi, wvo);

    if constexpr (NCC_B > 0) {
        #pragma unroll
        for (int b = 0; b < NB; ++b)
            conv_stage<NCC_B, ROWU_B, NW, NCH_B>(
                xin + (size_t)(b0 + b) * TR * XC, XC, NCC_A * 4, smem + b * SLABB, wv, lane);
        waitv<0>();
        hard_barrier();
        conv_phases<K, NCC_A, NCC_B * K, ROWU_B, OB32>(acc, wb, Xb, tg, lane, l31, hi, wvo);
    }

    // ---------------- epilogue: 3 t-sections through LDS ----------------
    constexpr int RCH = O_BLK / 8;
    float ps[8];
    if constexpr (POOL) {
        #pragma unroll
        for (int j = 0; j < 8; ++j) ps[j] = 0.f;
    }
    for (int g = 0; g < 3; ++g) {
        __syncthreads();
        if (wvt == g) {
            #pragma unroll
            for (int os = 0; os < 2; ++os) {
                #pragma unroll
                for (int rq = 0; rq < 4; ++rq) {
                    #pragma unroll
                    for (int rp = 0; rp < 2; ++rp) {
                        const int oc = wvo * 64 + os * 32 + 8 * rq + rp * 2 + 4 * hi;
                        const float bv0 = bb[oc], bv1 = bb[oc + 1];
                        const float g0 = gamma ? gamma[oc] * BN_INV : 1.f;
                        const float g1 = gamma ? gamma[oc + 1] * BN_INV : 1.f;
                        const float e0 = beta ? beta[oc] : 0.f;
                        const float e1 = beta ? beta[oc + 1] : 0.f;
                        const int r0 = rq * 4 + rp * 2;
                        #pragma unroll
                        for (int ts = 0; ts < 3; ++ts) {
                            float v0 = (acc[os][ts][r0] + bv0) * g0 + e0;
                            float v1 = (acc[os][ts][r0 + 1] + bv1) * g1 + e1;
                            int tl = ts * 32 + l31;
                            int byte = (bqw * 96 + tl) * O2 + ((oc * 2) ^ ((tl & 15) << 4));
                            __hip_bfloat162 pk;
                            pk.x = __float2bfloat16(v0);
                            pk.y = __float2bfloat16(v1);
                            *(__hip_bfloat162*)(smem + byte) = pk;
                        }
                    }
                }
            }
        }
        __syncthreads();
        for (int qq = tid; qq < NB * 96 * RCH; qq += NT) {
            int bql = qq / (96 * RCH), rem = qq - bql * (96 * RCH);
            int r = rem / RCH, cp = rem - r * RCH;
            int t = g * 96 + r;
            if (t >= Tt) continue;
            s16x8 hv = *(const s16x8*)(smem + (bql * 96 + r) * O2 + ((cp * 16) ^ ((r & 15) << 4)));
            size_t orow = ((size_t)(b0 + bql) * TR + t + 1) * O_BLK + cp * 8;
            s16x8 rv;
            if (HASRES) rv = *(const s16x8*)(res + orow);
            if constexpr (POOL) {
                #pragma unroll
                for (int j = 0; j < 8; ++j) {
                    float v = bf2f(hv[j]);
                    if (HASRES) v += bf2f(rv[j]);
                    if (GELU) v = gelu_f(v);
                    ps[j] += v;
                }
            } else {
                s16x8 ov;
                #pragma unroll
                for (int j = 0; j < 8; ++j) {
                    float v = bf2f(hv[j]);
                    if (HASRES) v += bf2f(rv[j]);
                    if (GELU) v = gelu_f(v);
                    ov[j] = f2bf(v);
                }
                *(s16x8*)(outp + orow) = ov;
            }
        }
    }

    if constexpr (POOL) {
        // per-thread ps[] covers fixed 8-channel slice cp=tid%RCH across its rows.
        constexpr int NRED = NT / RCH;   // threads per cp slice
        float* part = (float*)(smem + 96 * (size_t)O2);
        __syncthreads();
        #pragma unroll
        for (int j = 0; j < 8; ++j) part[tid * 8 + j] = ps[j];
        __syncthreads();
        if (tid < O_BLK) {
            int cp = tid >> 3, j = tid & 7;
            float s = 0.f;
            for (int r = 0; r < NRED; ++r) s += part[(cp + RCH * r) * 8 + j];
            pooled[(size_t)b0 * H2 + tid] = s * (1.0f / 281.0f);
        }
    }
}

// ---------------- head kernels ----------------

__global__ void head1_k(const float* __restrict__ pooled, const float* __restrict__ emb,
                        const int* __restrict__ sidx, const float* __restrict__ w1,
                        const float* __restrict__ b1, float* __restrict__ hout) {
    int idx = blockIdx.x * 256 + threadIdx.x;
    if (idx >= Bz * H1) return;
    int b = idx >> 7, j = idx & 127;
    const float* wr = w1 + (size_t)j * (H2 + ED);
    const float* pr = pooled + (size_t)b * H2;
    float a = b1[j];
    for (int i = 0; i < H2; ++i) a = fmaf(pr[i], wr[i], a);
    const float* er = emb + (size_t)sidx[b] * ED;
    #pragma unroll
    for (int e = 0; e < ED; ++e) a = fmaf(er[e], wr[H2 + e], a);
    hout[idx] = fmaxf(a, 0.f);
}

__global__ __launch_bounds__(256)
void head2_k(const float* __restrict__ h, const float* __restrict__ w2,
             const float* __restrict__ b2, float* __restrict__ out) {
    const int n0 = blockIdx.x * 64;
    const int b0 = blockIdx.y * 16;
    __shared__ float hs[16][128];
    __shared__ float w2s[64][129];
    const int tid = threadIdx.x;
    for (int idx = tid; idx < 16 * 128; idx += 256) {
        int bl = idx >> 7, j = idx & 127;
        hs[bl][j] = h[(size_t)(b0 + bl) * H1 + j];
    }
    for (int idx = tid; idx < 64 * 128; idx += 256) {
        int nl = idx >> 7, j = idx & 127;
        int n = n0 + nl;
        w2s[nl][j] = (n < NCLS) ? w2[(size_t)n * H1 + j] : 0.f;
    }
    __syncthreads();
    const int nl = tid & 63, bg = tid >> 6;
    float acc[4] = {0.f, 0.f, 0.f, 0.f};
    for (int j = 0; j < 128; ++j) {
        const float wv = w2s[nl][j];
        #pragma unroll
        for (int bb = 0; bb < 4; ++bb) acc[bb] = fmaf(wv, hs[bg * 4 + bb][j], acc[bb]);
    }
    const int n = n0 + nl;
    if (n < NCLS) {
        const float bv = b2[n];
        #pragma unroll
        for (int bb = 0; bb < 4; ++bb)
            out[(size_t)(b0 + bg * 4 + bb) * NCLS + n] = acc[bb] + bv;
    }
}

// ---------------- host launch ----------------

extern "C" void kernel_launch(void* const* d_in, const int* in_sizes, int n_in,
                              void* d_out, int out_size, void* d_ws, size_t ws_size,
                              hipStream_t stream) {
    const float* X      = (const float*)d_in[0];
    const int*   sidx   = (const int*)  d_in[1];
    const float* attn   = (const float*)d_in[2];
    const float* sa_w   = (const float*)d_in[3];
    const float* sa_b   = (const float*)d_in[4];
    const float* subj_w = (const float*)d_in[5];
    const float* subj_b = (const float*)d_in[6];
    const float* b1c1w = (const float*)d_in[7];  const float* b1c1b = (const float*)d_in[8];
    const float* b1c2w = (const float*)d_in[9];  const float* b1c2b = (const float*)d_in[10];
    const float* b1g1  = (const float*)d_in[11]; const float* b1be1 = (const float*)d_in[12];
    const float* b1g2  = (const float*)d_in[13]; const float* b1be2 = (const float*)d_in[14];
    const float* b2c1w = (const float*)d_in[15]; const float* b2c1b = (const float*)d_in[16];
    const float* b2c2w = (const float*)d_in[17]; const float* b2c2b = (const float*)d_in[18];
    const float* b2g1  = (const float*)d_in[19]; const float* b2be1 = (const float*)d_in[20];
    const float* b2g2  = (const float*)d_in[21]; const float* b2be2 = (const float*)d_in[22];
    const float* b2skw = (const float*)d_in[23]; const float* b2skb = (const float*)d_in[24];
    const float* b3c1w = (const float*)d_in[25]; const float* b3c1b = (const float*)d_in[26];
    const float* b3c2w = (const float*)d_in[27]; const float* b3c2b = (const float*)d_in[28];
    const float* b3g1  = (const float*)d_in[29]; const float* b3be1 = (const float*)d_in[30];
    const float* b3g2  = (const float*)d_in[31]; const float* b3be2 = (const float*)d_in[32];
    const float* emb   = (const float*)d_in[33];
    const float* hw1   = (const float*)d_in[34]; const float* hb1 = (const float*)d_in[35];
    const float* hw2   = (const float*)d_in[36]; const float* hb2 = (const float*)d_in[37];
    float* out = (float*)d_out;
    (void)in_sizes; (void)n_in; (void)out_size; (void)ws_size;

    char* wsp = (char*)d_ws;
    size_t off = 0;
    auto allocF = [&](size_t n) {
        float* p = (float*)(wsp + off);
        off += ((n * sizeof(float)) + 255) & ~(size_t)255;
        return p;
    };
    auto allocS = [&](size_t n) {
        short* p = (short*)(wsp + off);
        off += ((n * sizeof(short)) + 255) & ~(size_t)255;
        return p;
    };
    float* attnS   = allocF((size_t)C0 * C0);
    float* Mmat    = allocF((size_t)H1 * C0);
    float* biasS   = allocF((size_t)4 * H1);
    float* pooled  = allocF((size_t)Bz * H2);
    float* hbuf    = allocF((size_t)Bz * H1);
    short* wStageA = allocS((size_t)4 * 9 * 4 * 2 * 512);     // per-subj 36864
    short* wp_b1c1 = allocS((size_t)4 * 3 * 4 * 2 * 512);
    short* wp_b1c2 = allocS((size_t)4 * 3 * 4 * 2 * 512);
    short* wp_skip = allocS((size_t)4 * 1 * 8 * 2 * 512);
    short* wp_b2c1 = allocS((size_t)4 * 3 * 8 * 2 * 512);
    short* wp_b2c2 = allocS((size_t)8 * 3 * 8 * 2 * 512);
    short* wp_b3c1 = allocS((size_t)8 * 3 * 8 * 2 * 512);
    short* wp_b3c2 = allocS((size_t)8 * 3 * 8 * 2 * 512);
    short* xT   = allocS((size_t)Bz * TR * CP0 + 64);
    short* bufP = allocS((size_t)Bz * TR * H1);
    short* bufQ = allocS((size_t)Bz * TR * H1);
    short* bufR = allocS((size_t)Bz * TR * H2);
    short* bufS = allocS((size_t)Bz * TR * H2);

    // ---- zero margin rows ----
    zrows_k<<<Bz, 256, 0, stream>>>(xT, CP0);
    zrows_k<<<Bz, 256, 0, stream>>>(bufP, H1);
    zrows_k<<<Bz, 256, 0, stream>>>(bufQ, H1);
    zrows_k<<<Bz, 256, 0, stream>>>(bufR, H2);
    zrows_k<<<Bz, 256, 0, stream>>>(bufS, H2);

    // ---- prep ----
    softmax_rows_k<<<C0, 256, 0, stream>>>(attn, attnS, C0);
    gemm_M_k<<<(H1 * C0 + 255) / 256, 256, 0, stream>>>(sa_w, attnS, Mmat);
    msubA_k<<<(4 * 36864 + 255) / 256, 256, 0, stream>>>(subj_w, Mmat, wStageA);
    biasS_k<<<2, 256, 0, stream>>>(subj_w, sa_b, subj_b, biasS);
    wfrag_k<<<(4*3*4*2*512 + 255) / 256, 256, 0, stream>>>(b1c1w, wp_b1c1, 128, 128, 3, 4);
    wfrag_k<<<(4*3*4*2*512 + 255) / 256, 256, 0, stream>>>(b1c2w, wp_b1c2, 128, 128, 3, 4);
    wfrag_k<<<(4*1*8*2*512 + 255) / 256, 256, 0, stream>>>(b2skw, wp_skip, 128, 256, 1, 4);
    wfrag_k<<<(4*3*8*2*512 + 255) / 256, 256, 0, stream>>>(b2c1w, wp_b2c1, 128, 256, 3, 4);
    wfrag_k<<<(8*3*8*2*512 + 255) / 256, 256, 0, stream>>>(b2c2w, wp_b2c2, 256, 256, 3, 8);
    wfrag_k<<<(8*3*8*2*512 + 255) / 256, 256, 0, stream>>>(b3c1w, wp_b3c1, 256, 256, 3, 8);
    wfrag_k<<<(8*3*8*2*512 + 255) / 256, 256, 0, stream>>>(b3c2w, wp_b3c2, 256, 256, 3, 8);
    xpose_k<<<dim3(9, 9, Bz), dim3(32, 8), 0, stream>>>(X, xT);

    // ---- conv stack (phased kernels, full-T blocks) ----
    // stageA: xT(288ch) -> P(128), per-subject weights; 2 mega-phases (5+4 cc)
    convPH<1, 5, 24, 4, 16, 128, 2, 1, false, false, false><<<Bz, 384, 0, stream>>>(
        xT, CP0, wStageA, biasS, nullptr, nullptr, nullptr, bufP, nullptr, sidx, 36864, 128);
    // block1: P -> Q (gelu+bn); Q (+res P) -> P in-place   (NB=2)
    convPH<3, 4, 16, 0, 0, 128, 2, 2, true, false, false><<<Bz / 2, 768, 0, stream>>>(
        bufP, H1, wp_b1c1, b1c1b, b1g1, b1be1, nullptr, bufQ, nullptr, nullptr, 0, 0);
    convPH<3, 4, 16, 0, 0, 128, 2, 2, true, true, false><<<Bz / 2, 768, 0, stream>>>(
        bufQ, H1, wp_b1c2, b1c2b, b1g2, b1be2, bufP, bufP, nullptr, nullptr, 0, 0);
    // block2: skip P->S; c1 P->R; c2 R(+res S)->S in-place
    convPH<1, 4, 16, 0, 0, 256, 4, 1, false, false, false><<<Bz, 768, 0, stream>>>(
        bufP, H1, wp_skip, b2skb, nullptr, nullptr, nullptr, bufS, nullptr, nullptr, 0, 0);
    convPH<3, 4, 16, 0, 0, 256, 4, 1, true, false, false><<<Bz, 768, 0, stream>>>(
        bufP, H1, wp_b2c1, b2c1b, b2g1, b2be1, nullptr, bufR, nullptr, nullptr, 0, 0);
    convPH<3, 8, 32, 0, 0, 256, 4, 1, true, true, false><<<Bz, 768, 0, stream>>>(
        bufR, H2, wp_b2c2, b2c2b, b2g2, b2be2, bufS, bufS, nullptr, nullptr, 0, 0);
    // block3: c1 S->R; c2 R(+res S) -> fused global-avg-pool (no activation write)
    convPH<3, 8, 32, 0, 0, 256, 4, 1, true, false, false><<<Bz, 768, 0, stream>>>(
        bufS, H2, wp_b3c1, b3c1b, b3g1, b3be1, nullptr, bufR, nullptr, nullptr, 0, 0);
    convPH<3, 8, 32, 0, 0, 256, 4, 1, true, true, true><<<Bz, 768, 0, stream>>>(
        bufR, H2, wp_b3c2, b3c2b, b3g2, b3be2, bufS, nullptr, pooled, nullptr, 0, 0);

    // ---- head ----
    head1_k<<<(Bz * H1 + 255) / 256, 256, 0, stream>>>(pooled, emb, sidx, hw1, hb1, hbuf);
    head2_k<<<dim3((NCLS + 63) / 64, Bz / 16), 256, 0, stream>>>(hbuf, hw2, hb2, out);
}